// Round 1
// baseline (79.420 us; speedup 1.0000x reference)
//
#include <hip/hip_runtime.h>

// Single fused kernel.
// out[b, i*32+j, p*32+q] = sum_{s,t} U_st(enc_bi)[p] * V_st(enc_bj)[q]
// Each block owns (b, i, j0..j0+3): it recomputes the 5 needed encoder rows
// (x rows staged in LDS; W read once per block as a 5-row GEMM -> 64 MB total
// L2-hot W traffic), runs the 20 circuit-branch jobs (4 U + 16 V) in 3 passes
// of 8x32-lane groups (side is wave-uniform every pass), then does the 4
// outer products with 32 KB of nontemporal streaming stores.
// No workspace, no second launch, no inter-kernel drain.

typedef float vfloat4 __attribute__((ext_vector_type(4)));   // native vec for nontemporal builtin

__device__ __forceinline__ float2 shflx(float2 v, int mask) {
    return make_float2(__shfl_xor(v.x, mask, 64), __shfl_xor(v.y, mask, 64));
}

__global__ __launch_bounds__(256) void fused_kernel(const float* __restrict__ x,
                                                    const float* __restrict__ W,
                                                    const float* __restrict__ bt,
                                                    const float* __restrict__ rx0,
                                                    const float* __restrict__ ry0,
                                                    const float* __restrict__ ry1,
                                                    float* __restrict__ out,
                                                    int complex_out) {
    int bx = blockIdx.x;
    int b  = bx >> 8;            // batch
    int i  = (bx >> 3) & 31;     // U token
    int j0 = (bx & 7) * 4;       // V token group
    int tid = threadIdx.x;

    __shared__ float g1[10][8];      // layer1 RY*RX gate coeffs
    __shared__ float g2[10][2];      // layer2 RY: cy, sy
    __shared__ float sx[5][512];     // row 0: x_{b,i}; rows 1..4: x_{b,j0..j0+3}  (10 KB)
    __shared__ float eraw[5][32];
    __shared__ float e[5][32];       // normalized encodings
    __shared__ float2 su[128];       // U branches of enc_i
    __shared__ float2 sv[4][128];    // V branches of enc_{j0..j0+3}

    // gate coefficients: trig once per block
    if (tid < 10) {
        float sxv, cxv, s0, c0, s1, c1;
        sincosf(rx0[tid] * 0.5f, &sxv, &cxv);
        sincosf(ry0[tid] * 0.5f, &s0, &c0);
        sincosf(ry1[tid] * 0.5f, &s1, &c1);
        g1[tid][0] = c0 * cxv;  g1[tid][1] = s0 * sxv;    // g00
        g1[tid][2] = -s0 * cxv; g1[tid][3] = -c0 * sxv;   // g01
        g1[tid][4] = s0 * cxv;  g1[tid][5] = -c0 * sxv;   // g10
        g1[tid][6] = c0 * cxv;  g1[tid][7] = -s0 * sxv;   // g11
        g2[tid][0] = c1;        g2[tid][1] = s1;
    }

    // stage the 5 x rows into LDS (i row + 4 consecutive j rows)
    {
        const float4* xi = (const float4*)(x + (size_t)(b * 32 + i)  * 512);
        const float4* xj = (const float4*)(x + (size_t)(b * 32 + j0) * 512);
        if (tid < 128) ((float4*)&sx[0][0])[tid] = xi[tid];
        float4* dj = (float4*)&sx[1][0];             // rows 1..4 are contiguous (512 float4)
        dj[tid]       = xj[tid];
        dj[tid + 256] = xj[tid + 256];
    }
    __syncthreads();

    // 5-row GEMM-GEMV: col = tid>>3 (0..31), kk = tid&7 K-slice.
    // Each W float4 is read ONCE and FMA'd against all 5 x rows (from LDS).
    {
        int col = tid >> 3;
        int kk  = tid & 7;
        const float4* wp = (const float4*)(W + (size_t)col * 512 + kk * 4);
        float a0 = 0.f, a1 = 0.f, a2 = 0.f, a3 = 0.f, a4 = 0.f;
#pragma unroll
        for (int m = 0; m < 16; ++m) {
            float4 wv = wp[m * 8];
            int o = kk * 4 + m * 32;
            float4 v0 = *(const float4*)&sx[0][o];
            float4 v1 = *(const float4*)&sx[1][o];
            float4 v2 = *(const float4*)&sx[2][o];
            float4 v3 = *(const float4*)&sx[3][o];
            float4 v4 = *(const float4*)&sx[4][o];
            a0 += v0.x * wv.x + v0.y * wv.y + v0.z * wv.z + v0.w * wv.w;
            a1 += v1.x * wv.x + v1.y * wv.y + v1.z * wv.z + v1.w * wv.w;
            a2 += v2.x * wv.x + v2.y * wv.y + v2.z * wv.z + v2.w * wv.w;
            a3 += v3.x * wv.x + v3.y * wv.y + v3.z * wv.z + v3.w * wv.w;
            a4 += v4.x * wv.x + v4.y * wv.y + v4.z * wv.z + v4.w * wv.w;
        }
#pragma unroll
        for (int mask = 1; mask <= 4; mask <<= 1) {
            a0 += __shfl_xor(a0, mask, 64);
            a1 += __shfl_xor(a1, mask, 64);
            a2 += __shfl_xor(a2, mask, 64);
            a3 += __shfl_xor(a3, mask, 64);
            a4 += __shfl_xor(a4, mask, 64);
        }
        if (kk == 0) {
            eraw[0][col] = a0; eraw[1][col] = a1; eraw[2][col] = a2;
            eraw[3][col] = a3; eraw[4][col] = a4;
        }
    }
    __syncthreads();

    // L2-normalize each of the 5 encodings (rows aligned to 32-lane groups)
    if (tid < 160) {
        int r  = tid >> 5;
        int cc = tid & 31;
        float sum = eraw[r][cc] + bt[cc];
        float sq = sum * sum;
#pragma unroll
        for (int off = 1; off < 32; off <<= 1) sq += __shfl_xor(sq, off, 32);
        e[r][cc] = sum * (1.0f / sqrtf(sq));
    }
    __syncthreads();

    // 20 circuit jobs (U: row0 x 4 branches; V: rows1..4 x 4 branches) in 3
    // passes of 8 groups of 32 lanes. g = grpid + 8*pass keeps `side`
    // wave-uniform in every pass (pass0: waves0/1 side0, waves2/3 side1;
    // pass1: all side1; pass2: waves0/1 side1).
    for (int g = tid >> 5; g < 20; g += 8) {
        int side = (g >= 4) ? 1 : 0;
        int q    = g - 4;
        int br   = side ? (q & 3) : g;
        int erow = side ? (1 + (q >> 2)) : 0;
        int s = br >> 1, t = br & 1;
        int p = tid & 31;
        int wb = side * 5;
        float2 c = make_float2(e[erow][p], 0.f);
        // layer 1 butterflies
#pragma unroll
        for (int l = 0; l < 5; ++l) {
            int w = wb + l, bit = 1 << (4 - l);
            float2 pr = shflx(c, bit);
            float b0 = g1[w][0], b1 = g1[w][1], b2 = g1[w][2], b3 = g1[w][3];
            float b4 = g1[w][4], b5 = g1[w][5], b6 = g1[w][6], b7 = g1[w][7];
            float2 lo, hi;
            lo.x = b0 * c.x - b1 * c.y + b2 * pr.x - b3 * pr.y;
            lo.y = b0 * c.y + b1 * c.x + b2 * pr.y + b3 * pr.x;
            hi.x = b4 * pr.x - b5 * pr.y + b6 * c.x - b7 * c.y;
            hi.y = b4 * pr.y + b5 * pr.x + b6 * c.y + b7 * c.x;
            c = ((p & bit) == 0) ? lo : hi;
        }
        if (side == 0) {
#pragma unroll
            for (int l = 0; l < 4; ++l) {              // C_A chain
                int cb = 1 << (4 - l), tb = 1 << (3 - l);
                float2 pr = shflx(c, tb);
                if (p & cb) c = pr;
            }
            if ((p & 1) != s) c = make_float2(0.f, 0.f);   // P_s
            { float2 pr = shflx(c, 16); if (t) c = pr; }   // X_msb^t
        } else {
            { float2 pr = shflx(c, 16); if (s) c = pr; }   // X_msb^s
#pragma unroll
            for (int l = 0; l < 4; ++l) {              // C_B chain
                int cb = 1 << (4 - l), tb = 1 << (3 - l);
                float2 pr = shflx(c, tb);
                if (p & cb) c = pr;
            }
            if ((p & 1) != t) c = make_float2(0.f, 0.f);   // Q_t
        }
        // layer 2 RY
#pragma unroll
        for (int l = 0; l < 5; ++l) {
            int w = wb + l, bit = 1 << (4 - l);
            float cy = g2[w][0], sy = g2[w][1];
            float2 pr = shflx(c, bit);
            c = ((p & bit) == 0)
                  ? make_float2(cy * c.x - sy * pr.x, cy * c.y - sy * pr.y)
                  : make_float2(sy * pr.x + cy * c.x, sy * pr.y + cy * c.y);
        }
        if (side == 0) su[br * 32 + p] = c;
        else           sv[erow - 1][br * 32 + p] = c;
    }
    __syncthreads();

    // 4 outer products -> 32 KB nontemporal streaming store
    int d0 = tid << 2;               // 4 consecutive q-outputs per thread
    int pp = d0 >> 5;
    int q0 = d0 & 31;
    float2 up0 = su[pp], up1 = su[32 + pp], up2 = su[64 + pp], up3 = su[96 + pp];

#pragma unroll
    for (int jj = 0; jj < 4; ++jj) {
        const float2* svj = sv[jj];
        float2 acc[4];
#pragma unroll
        for (int ee = 0; ee < 4; ++ee) {
            int qq = q0 + ee;
            float2 w0 = svj[qq], w1 = svj[32 + qq], w2 = svj[64 + qq], w3 = svj[96 + qq];
            float2 a;
            a.x = up0.x * w0.x - up0.y * w0.y + up1.x * w1.x - up1.y * w1.y
                + up2.x * w2.x - up2.y * w2.y + up3.x * w3.x - up3.y * w3.y;
            a.y = up0.x * w0.y + up0.y * w0.x + up1.x * w1.y + up1.y * w1.x
                + up2.x * w2.y + up2.y * w2.x + up3.x * w3.y + up3.y * w3.x;
            acc[ee] = a;
        }
        size_t pair = (size_t)b * 1024 + (size_t)i * 32 + (j0 + jj);
        if (complex_out) {
            vfloat4* o = (vfloat4*)(out + (pair * 1024 + d0) * 2);
            vfloat4 w0 = {acc[0].x, acc[0].y, acc[1].x, acc[1].y};
            vfloat4 w1 = {acc[2].x, acc[2].y, acc[3].x, acc[3].y};
            __builtin_nontemporal_store(w0, o);
            __builtin_nontemporal_store(w1, o + 1);
        } else {
            vfloat4* o = (vfloat4*)(out + pair * 1024 + d0);
            vfloat4 w0 = {acc[0].x, acc[1].x, acc[2].x, acc[3].x};
            __builtin_nontemporal_store(w0, o);
        }
    }
}

extern "C" void kernel_launch(void* const* d_in, const int* in_sizes, int n_in,
                              void* d_out, int out_size, void* d_ws, size_t ws_size,
                              hipStream_t stream) {
    const float* x   = (const float*)d_in[0];   // (4,32,512)
    const float* W   = (const float*)d_in[1];   // (32,512)
    const float* bt  = (const float*)d_in[2];   // (32,)
    const float* rx0 = (const float*)d_in[3];   // (10,)
    const float* ry0 = (const float*)d_in[4];   // (10,)
    const float* ry1 = (const float*)d_in[5];   // (10,)

    (void)d_ws; (void)ws_size;                  // workspace no longer used

    int complex_out = (out_size > 4 * 1024 * 1024) ? 1 : 0;
    fused_kernel<<<1024, 256, 0, stream>>>(x, W, bt, rx0, ry0, ry1,
                                           (float*)d_out, complex_out);
}

// Round 2
// 75.241 us; speedup vs baseline: 1.0556x; 1.0556x over previous
//
#include <hip/hip_runtime.h>

// Two-kernel pipeline (round-0 structure, K2 re-split for occupancy).
// out[b, i*32+j, p*32+q] = sum_{s,t} U_st(enc_bi)[p] * V_st(enc_bj)[q]
// K1: 128 blocks (one enc row each): gate-table trig + coalesced GEMV +
//     8 circuit-branch jobs (8 half-wave groups, one pass) -> U,V in ws.
// K2: 2048 blocks (b, i, j0..j0+1): coalesced U/V load -> 2 outer products
//     -> 16 KB nontemporal streaming store. 8 blocks/CU (3 KB LDS) so the
//     store pipe has 32 waves/CU issuing.

typedef float vfloat4 __attribute__((ext_vector_type(4)));   // native vec for nontemporal builtin

__device__ __forceinline__ float2 shflx(float2 v, int mask) {
    return make_float2(__shfl_xor(v.x, mask, 64), __shfl_xor(v.y, mask, 64));
}

// ---------------- K1: prep ----------------
__global__ __launch_bounds__(256) void prep_kernel(const float* __restrict__ x,
                                                   const float* __restrict__ W,
                                                   const float* __restrict__ bt,
                                                   const float* __restrict__ rx0,
                                                   const float* __restrict__ ry0,
                                                   const float* __restrict__ ry1,
                                                   float2* __restrict__ U,
                                                   float2* __restrict__ V) {
    int row = blockIdx.x;            // 0..127 = b*32 + token
    int tid = threadIdx.x;

    __shared__ float g1[10][8];      // layer1 RY*RX gate coeffs
    __shared__ float g2[10][2];      // layer2 RY: cy, sy
    __shared__ float esum[32];
    __shared__ float e[32];

    // gate coefficients: trig once per block
    if (tid < 10) {
        float sx, cx, s0, c0, s1, c1;
        sincosf(rx0[tid] * 0.5f, &sx, &cx);
        sincosf(ry0[tid] * 0.5f, &s0, &c0);
        sincosf(ry1[tid] * 0.5f, &s1, &c1);
        g1[tid][0] = c0 * cx;  g1[tid][1] = s0 * sx;    // g00
        g1[tid][2] = -s0 * cx; g1[tid][3] = -c0 * sx;   // g01
        g1[tid][4] = s0 * cx;  g1[tid][5] = -c0 * sx;   // g10
        g1[tid][6] = c0 * cx;  g1[tid][7] = -s0 * sx;   // g11
        g2[tid][0] = c1;       g2[tid][1] = s1;
    }

    // GEMV: col = tid>>3 (0..31), kk = tid&7 K-slice; W reads 128B-contig per 8 lanes
    {
        int col = tid >> 3;
        int kk  = tid & 7;
        const float4* wp = (const float4*)(W + (size_t)col * 512 + kk * 4);
        const float4* xp = (const float4*)(x + (size_t)row * 512 + kk * 4);
        float acc = 0.f;
#pragma unroll
        for (int m = 0; m < 16; ++m) {
            float4 wv = wp[m * 8];
            float4 xv = xp[m * 8];
            acc += xv.x * wv.x + xv.y * wv.y + xv.z * wv.z + xv.w * wv.w;
        }
        acc += __shfl_xor(acc, 1, 64);
        acc += __shfl_xor(acc, 2, 64);
        acc += __shfl_xor(acc, 4, 64);
        if (kk == 0) esum[col] = acc;
    }
    __syncthreads();

    if (tid < 32) {
        float sum = esum[tid] + bt[tid];
        float sq = sum * sum;
#pragma unroll
        for (int off = 1; off < 32; off <<= 1) sq += __shfl_xor(sq, off, 64);
        e[tid] = sum * (1.0f / sqrtf(sq));
    }
    __syncthreads();

    // 8 circuit jobs on 8 half-wave groups: grp = side*4 + br; side wave-uniform
    {
        int grp = tid >> 5;          // 0..7
        int side = grp >> 2;         // waves 0,1 -> side 0 ; waves 2,3 -> side 1
        int br = grp & 3;
        int s = br >> 1, t = br & 1;
        int p = tid & 31;
        int wb = side * 5;
        float2 c = make_float2(e[p], 0.f);
        // layer 1 butterflies
#pragma unroll
        for (int l = 0; l < 5; ++l) {
            int w = wb + l, bit = 1 << (4 - l);
            float2 pr = shflx(c, bit);
            float a0 = g1[w][0], a1 = g1[w][1], a2 = g1[w][2], a3 = g1[w][3];
            float a4 = g1[w][4], a5 = g1[w][5], a6 = g1[w][6], a7 = g1[w][7];
            float2 lo, hi;
            lo.x = a0 * c.x - a1 * c.y + a2 * pr.x - a3 * pr.y;
            lo.y = a0 * c.y + a1 * c.x + a2 * pr.y + a3 * pr.x;
            hi.x = a4 * pr.x - a5 * pr.y + a6 * c.x - a7 * c.y;
            hi.y = a4 * pr.y + a5 * pr.x + a6 * c.y + a7 * c.x;
            c = ((p & bit) == 0) ? lo : hi;
        }
        if (side == 0) {
#pragma unroll
            for (int l = 0; l < 4; ++l) {              // C_A chain
                int cb = 1 << (4 - l), tb = 1 << (3 - l);
                float2 pr = shflx(c, tb);
                if (p & cb) c = pr;
            }
            if ((p & 1) != s) c = make_float2(0.f, 0.f);   // P_s
            { float2 pr = shflx(c, 16); if (t) c = pr; }   // X_msb^t
        } else {
            { float2 pr = shflx(c, 16); if (s) c = pr; }   // X_msb^s
#pragma unroll
            for (int l = 0; l < 4; ++l) {              // C_B chain
                int cb = 1 << (4 - l), tb = 1 << (3 - l);
                float2 pr = shflx(c, tb);
                if (p & cb) c = pr;
            }
            if ((p & 1) != t) c = make_float2(0.f, 0.f);   // Q_t
        }
        // layer 2 RY
#pragma unroll
        for (int l = 0; l < 5; ++l) {
            int w = wb + l, bit = 1 << (4 - l);
            float cy = g2[w][0], sy = g2[w][1];
            float2 pr = shflx(c, bit);
            c = ((p & bit) == 0)
                  ? make_float2(cy * c.x - sy * pr.x, cy * c.y - sy * pr.y)
                  : make_float2(sy * pr.x + cy * c.x, sy * pr.y + cy * c.y);
        }
        float2* dst = (side == 0) ? U : V;
        dst[(size_t)row * 128 + br * 32 + p] = c;
    }
}

// ---------------- K2: outer products ----------------
// grid 2048: b = bx>>9, i = (bx>>4)&31, j0 = (bx&15)*2 ; block 256
__global__ __launch_bounds__(256) void outer_kernel(const float2* __restrict__ U,
                                                    const float2* __restrict__ V,
                                                    float* __restrict__ out,
                                                    int complex_out) {
    int bx = blockIdx.x;
    int b  = bx >> 9;
    int i  = (bx >> 4) & 31;
    int j0 = (bx & 15) * 2;
    int tid = threadIdx.x;

    __shared__ float2 su[128];       // U branches of enc_i        (1 KB)
    __shared__ float2 sv[2][128];    // V branches of enc_{j0,j0+1} (2 KB)

    if (tid < 128) {
        ((float4*)sv)[tid] = ((const float4*)(V + (size_t)(b * 32 + j0) * 128))[tid];
    } else if (tid < 192) {
        ((float4*)su)[tid - 128] = ((const float4*)(U + (size_t)(b * 32 + i) * 128))[tid - 128];
    }
    __syncthreads();

    int d0 = tid << 2;               // 4 consecutive q-outputs per thread
    int pp = d0 >> 5;
    int q0 = d0 & 31;
    float2 up0 = su[pp], up1 = su[32 + pp], up2 = su[64 + pp], up3 = su[96 + pp];

#pragma unroll
    for (int jj = 0; jj < 2; ++jj) {
        const float2* svj = sv[jj];
        float2 acc[4];
#pragma unroll
        for (int ee = 0; ee < 4; ++ee) {
            int q = q0 + ee;
            float2 v0 = svj[q], v1 = svj[32 + q], v2 = svj[64 + q], v3 = svj[96 + q];
            float2 a;
            a.x = up0.x * v0.x - up0.y * v0.y + up1.x * v1.x - up1.y * v1.y
                + up2.x * v2.x - up2.y * v2.y + up3.x * v3.x - up3.y * v3.y;
            a.y = up0.x * v0.y + up0.y * v0.x + up1.x * v1.y + up1.y * v1.x
                + up2.x * v2.y + up2.y * v2.x + up3.x * v3.y + up3.y * v3.x;
            acc[ee] = a;
        }
        size_t pair = (size_t)b * 1024 + (size_t)i * 32 + (j0 + jj);
        if (complex_out) {
            vfloat4* o = (vfloat4*)(out + (pair * 1024 + d0) * 2);
            vfloat4 w0 = {acc[0].x, acc[0].y, acc[1].x, acc[1].y};
            vfloat4 w1 = {acc[2].x, acc[2].y, acc[3].x, acc[3].y};
            __builtin_nontemporal_store(w0, o);
            __builtin_nontemporal_store(w1, o + 1);
        } else {
            vfloat4* o = (vfloat4*)(out + pair * 1024 + d0);
            vfloat4 w0 = {acc[0].x, acc[1].x, acc[2].x, acc[3].x};
            __builtin_nontemporal_store(w0, o);
        }
    }
}

extern "C" void kernel_launch(void* const* d_in, const int* in_sizes, int n_in,
                              void* d_out, int out_size, void* d_ws, size_t ws_size,
                              hipStream_t stream) {
    const float* x   = (const float*)d_in[0];   // (4,32,512)
    const float* W   = (const float*)d_in[1];   // (32,512)
    const float* bt  = (const float*)d_in[2];   // (32,)
    const float* rx0 = (const float*)d_in[3];   // (10,)
    const float* ry0 = (const float*)d_in[4];   // (10,)
    const float* ry1 = (const float*)d_in[5];   // (10,)

    // ws layout (float2): U 128*128 | V 128*128  (256 KB total)
    float2* U = (float2*)d_ws;
    float2* V = U + 16384;

    prep_kernel<<<128, 256, 0, stream>>>(x, W, bt, rx0, ry0, ry1, U, V);

    int complex_out = (out_size > 4 * 1024 * 1024) ? 1 : 0;
    outer_kernel<<<2048, 256, 0, stream>>>(U, V, (float*)d_out, complex_out);
}